// Round 3
// baseline (1212.804 us; speedup 1.0000x reference)
//
#include <hip/hip_runtime.h>
#include <hip/hip_bf16.h>

typedef __bf16 bf16x8 __attribute__((ext_vector_type(8)));
typedef float f32x4 __attribute__((ext_vector_type(4)));
typedef unsigned short u16;
typedef unsigned int u32;

#define M_ROWS 8192
#define DMODEL 2048
#define DFFN   8192

__device__ __forceinline__ u16 f2bf(float f) {
  u32 u = __float_as_uint(f);
  u32 r = u + 0x7fffu + ((u >> 16) & 1u);
  return (u16)(r >> 16);
}

__device__ __forceinline__ void async16(const void* g, void* l) {
  __builtin_amdgcn_global_load_lds((const __attribute__((address_space(1))) u32*)g,
                                   (__attribute__((address_space(3))) u32*)l, 16, 0, 0);
}

// ---------------- fp32 -> bf16 elementwise (x) ----------------
__global__ void conv_bf16x4(const float* __restrict__ in, u16* __restrict__ out, int n4) {
  int i = blockIdx.x * blockDim.x + threadIdx.x;
  if (i >= n4) return;
  float4 v = reinterpret_cast<const float4*>(in)[i];
  ushort4 o;
  o.x = f2bf(v.x); o.y = f2bf(v.y); o.z = f2bf(v.z); o.w = f2bf(v.w);
  reinterpret_cast<ushort4*>(out)[i] = o;
}

// ------------- transpose + convert (weights -> B^T bf16) -------------
template <int ILV>
__global__ void transpose_conv(const float* __restrict__ in, u16* __restrict__ out,
                               int R, int C, int sel) {
  __shared__ float tl[64][65];
  const int t = threadIdx.x;
  const int r0 = blockIdx.y * 64, c0 = blockIdx.x * 64;
#pragma unroll
  for (int pr = 0; pr < 4; ++pr) {
    int rl = pr * 16 + (t >> 4);
    int cl = (t & 15) * 4;
    float4 v = *reinterpret_cast<const float4*>(&in[(size_t)(r0 + rl) * C + c0 + cl]);
    tl[rl][cl] = v.x; tl[rl][cl + 1] = v.y; tl[rl][cl + 2] = v.z; tl[rl][cl + 3] = v.w;
  }
  __syncthreads();
#pragma unroll
  for (int pc = 0; pc < 4; ++pc) {
    int cl = pc * 16 + (t >> 4);
    int rl = (t & 15) * 4;
    ushort4 o;
    o.x = f2bf(tl[rl + 0][cl]); o.y = f2bf(tl[rl + 1][cl]);
    o.z = f2bf(tl[rl + 2][cl]); o.w = f2bf(tl[rl + 3][cl]);
    int c = c0 + cl;
    int v = ILV ? ((c >> 4) * 32 + sel * 16 + (c & 15)) : c;
    *reinterpret_cast<ushort4*>(&out[(size_t)v * R + r0 + rl]) = o;
  }
}

// ---------------- top-k indices -> bitmask (int32/int64 robust) ----------------
__global__ void build_mask(const u32* __restrict__ idxw, u32* __restrict__ mask, int total) {
  int i = blockIdx.x * blockDim.x + threadIdx.x;
  if (i >= total) return;
  bool is64 = (idxw[1] == 0u);
  int m = i >> 9;  // 512 indices per row
  int j = is64 ? (int)idxw[2 * i] : (int)idxw[i];
  atomicOr(&mask[(size_t)m * 256 + (j >> 5)], 1u << (j & 31));
}

// ---------------- GEMM core: C = A @ B^T, counted-vmcnt 3-stage pipeline ----------------
// BM=256, BN=128, BK=64. 512 threads = 8 waves (4M x 2N), wave tile 64x64 (4x4 frags).
// LDS ring: 3 stages x (A 32KB + B 16KB). Iter t: compute tile t from stage[t%3],
// prefetch tile t+2 into stage[(t+2)%3] (6 loads/thread split 3+3 across 2 phases).
// vmcnt(6) at phase B proves tile t+1 landed (its loads are older than t's 6 issues).
// MODE 0: interleaved gate/up virtual cols -> Z = mask * silu(g) * u (bf16)
// MODE 1: fp32 store [.][DMODEL]
template <int MODE, int NBX, int NBY>
__global__ __launch_bounds__(512, 2)
void gemm_bt(const u16* __restrict__ A, const u16* __restrict__ B, int K,
             void* __restrict__ outp, const u32* __restrict__ mask) {
  constexpr int T = NBX * NBY;
  constexpr int CHUNK = T / 8;   // T % 8 == 0
  constexpr int GM = 4;          // NBY % 4 == 0; band of 4 shares one B panel (~4.5MB/L2)
  constexpr int BAND = GM * NBX;
  int id = blockIdx.x;
  id = (id & 7) * CHUNK + (id >> 3);          // bijective XCD chunking
  const int by = (id / BAND) * GM + (id % BAND) % GM;
  const int bx = (id % BAND) / GM;

  __shared__ __align__(16) char smem[3 * 49152];  // 144 KB

  const int tid = threadIdx.x;
  const int lane = tid & 63;
  const int wave = tid >> 6;
  const int wr = wave >> 1, wc = wave & 1;    // 4M x 2N wave grid
  const int lrow = lane & 15;
  const int lkb = (lane >> 4) << 4;

  // LDS read byte-offsets (swizzled, proven 0-conflict layout: rows of 128B)
  int aoff[4][2], boff[4][2];
#pragma unroll
  for (int m = 0; m < 4; ++m) {
    int row = wr * 64 + m * 16 + lrow;
#pragma unroll
    for (int kk = 0; kk < 2; ++kk)
      aoff[m][kk] = row * 128 + ((kk * 64 + lkb) ^ ((row & 7) << 4));
  }
#pragma unroll
  for (int n = 0; n < 4; ++n) {
    int row = wc * 64 + n * 16 + lrow;
#pragma unroll
    for (int kk = 0; kk < 2; ++kk)
      boff[n][kk] = row * 128 + ((kk * 64 + lkb) ^ ((row & 7) << 4));
  }

  const size_t ldab = (size_t)K * 2;
  const char* Ab = (const char*)A + (size_t)by * 256 * ldab;
  const char* Bb = (const char*)B + (size_t)bx * 128 * ldab;

  // staging source offsets: linear LDS dest, inverse-swizzled global source (rule #21)
  size_t gA[4], gB[2];
#pragma unroll
  for (int i = 0; i < 4; ++i) {
    int X = i * 8192 + tid * 16;
    int srow = X >> 7;
    gA[i] = (size_t)srow * ldab + (size_t)((X & 127) ^ ((srow & 7) << 4));
  }
#pragma unroll
  for (int i = 0; i < 2; ++i) {
    int X = i * 8192 + tid * 16;
    int srow = X >> 7;
    gB[i] = (size_t)srow * ldab + (size_t)((X & 127) ^ ((srow & 7) << 4));
  }

  const int nkt = K >> 6;
  // prologue: stage tile 0 -> s0, tile 1 -> s1 (6 loads each)
#pragma unroll
  for (int i = 0; i < 4; ++i) async16(Ab + gA[i], smem + i * 8192 + wave * 1024);
#pragma unroll
  for (int i = 0; i < 2; ++i) async16(Bb + gB[i], smem + 32768 + i * 8192 + wave * 1024);
#pragma unroll
  for (int i = 0; i < 4; ++i) async16(Ab + 128 + gA[i], smem + 49152 + i * 8192 + wave * 1024);
#pragma unroll
  for (int i = 0; i < 2; ++i) async16(Bb + 128 + gB[i], smem + 49152 + 32768 + i * 8192 + wave * 1024);
  asm volatile("s_waitcnt vmcnt(6)" ::: "memory");  // tile 0 landed, tile 1 in flight
  __builtin_amdgcn_s_barrier();

  f32x4 acc[4][4];
#pragma unroll
  for (int m = 0; m < 4; ++m)
#pragma unroll
    for (int n = 0; n < 4; ++n) acc[m][n] = (f32x4){0.f, 0.f, 0.f, 0.f};

  int s = 0;
  for (int t = 0; t < nkt; ++t) {
    const char* As = smem + s * 49152;
    const char* Bs = As + 32768;
    char* SdA = smem + ((s == 0) ? 2 : s - 1) * 49152;  // (s+2)%3
    char* SdB = SdA + 32768;
    const bool pf = (t + 2 < nkt);
    const size_t kb = (size_t)(t + 2) * 128;

    // ================= phase A =================
    if (pf) {
      async16(Ab + kb + gA[0], SdA + 0 * 8192 + wave * 1024);
      async16(Ab + kb + gA[1], SdA + 1 * 8192 + wave * 1024);
      async16(Bb + kb + gB[0], SdB + 0 * 8192 + wave * 1024);
    }
    bf16x8 af[4][2], bf[2][2];
#pragma unroll
    for (int m = 0; m < 4; ++m)
#pragma unroll
      for (int kk = 0; kk < 2; ++kk)
        af[m][kk] = *reinterpret_cast<const bf16x8*>(As + aoff[m][kk]);
#pragma unroll
    for (int n = 0; n < 2; ++n)
#pragma unroll
      for (int kk = 0; kk < 2; ++kk)
        bf[n][kk] = *reinterpret_cast<const bf16x8*>(Bs + boff[n][kk]);
    __builtin_amdgcn_sched_barrier(0);
    __builtin_amdgcn_s_barrier();
    __builtin_amdgcn_s_setprio(1);
#pragma unroll
    for (int m = 0; m < 4; ++m)
#pragma unroll
      for (int n = 0; n < 2; ++n)
#pragma unroll
        for (int kk = 0; kk < 2; ++kk)
          acc[m][n] = __builtin_amdgcn_mfma_f32_16x16x32_bf16(af[m][kk], bf[n][kk], acc[m][n], 0, 0, 0);
    __builtin_amdgcn_s_setprio(0);
    __builtin_amdgcn_sched_barrier(0);
    __builtin_amdgcn_s_barrier();

    // ================= phase B =================
    if (pf) {
      async16(Ab + kb + gA[2], SdA + 2 * 8192 + wave * 1024);
      async16(Ab + kb + gA[3], SdA + 3 * 8192 + wave * 1024);
      async16(Bb + kb + gB[1], SdB + 1 * 8192 + wave * 1024);
    }
    bf16x8 bg[2][2];
#pragma unroll
    for (int n = 0; n < 2; ++n)
#pragma unroll
      for (int kk = 0; kk < 2; ++kk)
        bg[n][kk] = *reinterpret_cast<const bf16x8*>(Bs + boff[2 + n][kk]);
    __builtin_amdgcn_sched_barrier(0);
    if (pf) asm volatile("s_waitcnt vmcnt(6)" ::: "memory");   // tile t+1 fully landed
    else    asm volatile("s_waitcnt vmcnt(0)" ::: "memory");   // tail drain
    __builtin_amdgcn_s_barrier();
    __builtin_amdgcn_s_setprio(1);
#pragma unroll
    for (int m = 0; m < 4; ++m)
#pragma unroll
      for (int n = 0; n < 2; ++n)
#pragma unroll
        for (int kk = 0; kk < 2; ++kk)
          acc[m][2 + n] = __builtin_amdgcn_mfma_f32_16x16x32_bf16(af[m][kk], bg[n][kk], acc[m][2 + n], 0, 0, 0);
    __builtin_amdgcn_s_setprio(0);
    __builtin_amdgcn_sched_barrier(0);
    __builtin_amdgcn_s_barrier();

    s = (s == 2) ? 0 : s + 1;
  }

  if (MODE == 0) {
    u16* Z = (u16*)outp;
    const int colw = bx * 2 + wc;  // mask word: g16>>1, g16 = bx*4+wc*2+p
#pragma unroll
    for (int m = 0; m < 4; ++m) {
#pragma unroll
      for (int j = 0; j < 4; ++j) {
        int gr = by * 256 + wr * 64 + m * 16 + ((lane >> 4) << 2) + j;
        u32 w = mask[(size_t)gr * 256 + colw];
#pragma unroll
        for (int p = 0; p < 2; ++p) {
          float g = acc[m][2 * p][j];
          float u = acc[m][2 * p + 1][j];
          float z = 0.f;
          if ((w >> (p * 16 + lrow)) & 1u) z = g * u / (1.f + __expf(-g));
          int gc = (bx * 4 + wc * 2 + p) * 16 + lrow;
          Z[(size_t)gr * DFFN + gc] = f2bf(z);
        }
      }
    }
  } else {
    float* O = (float*)outp;
#pragma unroll
    for (int m = 0; m < 4; ++m) {
#pragma unroll
      for (int j = 0; j < 4; ++j) {
        int gr = by * 256 + wr * 64 + m * 16 + ((lane >> 4) << 2) + j;
#pragma unroll
        for (int n = 0; n < 4; ++n) {
          int gc = bx * 128 + wc * 64 + n * 16 + lrow;
          O[(size_t)gr * DMODEL + gc] = acc[m][n][j];
        }
      }
    }
  }
}

extern "C" void kernel_launch(void* const* d_in, const int* in_sizes, int n_in,
                              void* d_out, int out_size, void* d_ws, size_t ws_size,
                              hipStream_t stream) {
  (void)in_sizes; (void)n_in; (void)out_size; (void)ws_size;
  const float* x   = (const float*)d_in[0];
  const u32*   ix  = (const u32*)d_in[1];
  const float* wg  = (const float*)d_in[2];
  const float* wu  = (const float*)d_in[3];
  const float* wd  = (const float*)d_in[4];

  // ws layout (232 MB): [0,32) xb (then wdT aliases); [32,96) wcomb; [96,224) Zb; [224,232) mask
  char* ws = (char*)d_ws;
  u16* xb    = (u16*)(ws);
  u16* wcomb = (u16*)(ws + (size_t)32 * 1048576);
  u16* Zb    = (u16*)(ws + (size_t)96 * 1048576);
  u32* mask  = (u32*)(ws + (size_t)224 * 1048576);
  u16* wdT   = (u16*)(ws);  // aliases xb, used only after GEMM1

  conv_bf16x4<<<(M_ROWS * DMODEL / 4 + 255) / 256, 256, 0, stream>>>(x, xb, M_ROWS * DMODEL / 4);
  dim3 tgrid(DFFN / 64, DMODEL / 64);
  transpose_conv<1><<<tgrid, 256, 0, stream>>>(wg, wcomb, DMODEL, DFFN, 0);
  transpose_conv<1><<<tgrid, 256, 0, stream>>>(wu, wcomb, DMODEL, DFFN, 1);
  hipMemsetAsync(mask, 0, (size_t)M_ROWS * 256 * 4, stream);
  build_mask<<<(M_ROWS * 512 + 255) / 256, 256, 0, stream>>>(ix, mask, M_ROWS * 512);
  // GEMM1: virtual N = 16384 interleaved gate/up
  gemm_bt<0, 2 * DFFN / 128, M_ROWS / 256>
      <<<(2 * DFFN / 128) * (M_ROWS / 256), 512, 0, stream>>>(xb, wcomb, DMODEL, Zb, mask);
  dim3 dgrid(DMODEL / 64, DFFN / 64);
  transpose_conv<0><<<dgrid, 256, 0, stream>>>(wd, wdT, DFFN, DMODEL, 0);
  // GEMM2: Y = Z @ Wd
  gemm_bt<1, DMODEL / 128, M_ROWS / 256>
      <<<(DMODEL / 128) * (M_ROWS / 256), 512, 0, stream>>>(Zb, wdT, DFFN, d_out, nullptr);
}

// Round 4
// 1172.393 us; speedup vs baseline: 1.0345x; 1.0345x over previous
//
#include <hip/hip_runtime.h>
#include <hip/hip_bf16.h>

typedef __bf16 bf16x8 __attribute__((ext_vector_type(8)));
typedef float f32x4 __attribute__((ext_vector_type(4)));
typedef unsigned short u16;
typedef unsigned int u32;

#define M_ROWS 8192
#define DMODEL 2048
#define DFFN   8192

__device__ __forceinline__ u16 f2bf(float f) {
  u32 u = __float_as_uint(f);
  u32 r = u + 0x7fffu + ((u >> 16) & 1u);
  return (u16)(r >> 16);
}

__device__ __forceinline__ void async16(const void* g, void* l) {
  __builtin_amdgcn_global_load_lds((const __attribute__((address_space(1))) u32*)g,
                                   (__attribute__((address_space(3))) u32*)l, 16, 0, 0);
}

// ---------------- fp32 -> bf16 elementwise (x) ----------------
__global__ void conv_bf16x4(const float* __restrict__ in, u16* __restrict__ out, int n4) {
  int i = blockIdx.x * blockDim.x + threadIdx.x;
  if (i >= n4) return;
  float4 v = reinterpret_cast<const float4*>(in)[i];
  ushort4 o;
  o.x = f2bf(v.x); o.y = f2bf(v.y); o.z = f2bf(v.z); o.w = f2bf(v.w);
  reinterpret_cast<ushort4*>(out)[i] = o;
}

// ------------- transpose + convert (weights -> B^T bf16) -------------
template <int ILV>
__global__ void transpose_conv(const float* __restrict__ in, u16* __restrict__ out,
                               int R, int C, int sel) {
  __shared__ float tl[64][65];
  const int t = threadIdx.x;
  const int r0 = blockIdx.y * 64, c0 = blockIdx.x * 64;
#pragma unroll
  for (int pr = 0; pr < 4; ++pr) {
    int rl = pr * 16 + (t >> 4);
    int cl = (t & 15) * 4;
    float4 v = *reinterpret_cast<const float4*>(&in[(size_t)(r0 + rl) * C + c0 + cl]);
    tl[rl][cl] = v.x; tl[rl][cl + 1] = v.y; tl[rl][cl + 2] = v.z; tl[rl][cl + 3] = v.w;
  }
  __syncthreads();
#pragma unroll
  for (int pc = 0; pc < 4; ++pc) {
    int cl = pc * 16 + (t >> 4);
    int rl = (t & 15) * 4;
    ushort4 o;
    o.x = f2bf(tl[rl + 0][cl]); o.y = f2bf(tl[rl + 1][cl]);
    o.z = f2bf(tl[rl + 2][cl]); o.w = f2bf(tl[rl + 3][cl]);
    int c = c0 + cl;
    int v = ILV ? ((c >> 4) * 32 + sel * 16 + (c & 15)) : c;
    *reinterpret_cast<ushort4*>(&out[(size_t)v * R + r0 + rl]) = o;
  }
}

// ---------------- top-k indices -> bitmask (int32/int64 robust) ----------------
__global__ void build_mask(const u32* __restrict__ idxw, u32* __restrict__ mask, int total) {
  int i = blockIdx.x * blockDim.x + threadIdx.x;
  if (i >= total) return;
  bool is64 = (idxw[1] == 0u);
  int m = i >> 9;  // 512 indices per row
  int j = is64 ? (int)idxw[2 * i] : (int)idxw[i];
  atomicOr(&mask[(size_t)m * 256 + (j >> 5)], 1u << (j & 31));
}

// ---- MFMA quadrant: 4 M-frags x 2 N-frags x 2 k-slices = 16 MFMA ----
template <int HM, int HN>
__device__ __forceinline__ void quad(f32x4 (&acc)[8][4], const bf16x8 (&af)[4][2],
                                     const bf16x8 (&bfr)[2][2]) {
#pragma unroll
  for (int m = 0; m < 4; ++m)
#pragma unroll
    for (int n = 0; n < 2; ++n)
#pragma unroll
      for (int kk = 0; kk < 2; ++kk)
        acc[HM * 4 + m][HN * 2 + n] =
            __builtin_amdgcn_mfma_f32_16x16x32_bf16(af[m][kk], bfr[n][kk],
                                                    acc[HM * 4 + m][HN * 2 + n], 0, 0, 0);
}

// =================== GEMM core: C = A @ B^T, m201-style 8-phase ===================
// BM=BN=256, BK=64. 512 thr = 8 waves (2M x 4N). Per-wave output 128x64, but SPLIT:
// wave rows = hm*128 + wr*64 + m*16 (spans both A-halves), cols = hn*128 + wc*32 + n*16.
// So phase (hm,hn) has ALL waves reading only A-half hm + B-half hn -> halves free early.
// LDS: 2 buffers x {A0,A1,B0,B1} halves of 16KB = 128KB. Phase order Q00,Q01,Q10,Q11.
// Frees: A0 after P2, B0 after P3, A1/B1 after P4.  Stage schedule (ledger-verified):
//   t.P1: B1(t+1)   t.P2: A1(t+1)   t.P3: A0(t+2)   t.P4: B0(t+2)
// vmcnt(4) at each P4 only (2 half-tiles in flight); tail: vmcnt(0) when t+2>=nkt.
// MODE 0: interleaved gate/up virtual cols -> Z = mask*silu(g)*u (bf16). MODE 1: fp32.
template <int MODE, int NBX, int NBY>
__global__ __launch_bounds__(512, 2)
void gemm_bt(const u16* __restrict__ A, const u16* __restrict__ B, int K,
             void* __restrict__ outp, const u32* __restrict__ mask) {
  constexpr int T = NBX * NBY;
  constexpr int CHUNK = T / 8;
  constexpr int GM = 4;
  constexpr int BAND = GM * NBX;
  int id = blockIdx.x;
  id = (id & 7) * CHUNK + (id >> 3);
  const int by = (id / BAND) * GM + (id % BAND) % GM;
  const int bx = (id % BAND) / GM;

  __shared__ __align__(16) char smem[131072];  // 2 x 64KB

  const int tid = threadIdx.x;
  const int lane = tid & 63;
  const int wave = tid >> 6;
  const int wr = wave >> 2;        // 0..1
  const int wc = wave & 3;         // 0..3
  const int lrow = lane & 15;
  const int lkb = (lane >> 4) << 4;

  // within-half swizzled ds_read byte offsets
  int aoff[4][2], boff[2][2];
#pragma unroll
  for (int m = 0; m < 4; ++m) {
    int r = wr * 64 + m * 16 + lrow;
#pragma unroll
    for (int kk = 0; kk < 2; ++kk)
      aoff[m][kk] = r * 128 + ((kk * 64 + lkb) ^ ((r & 7) << 4));
  }
#pragma unroll
  for (int n = 0; n < 2; ++n) {
    int r = wc * 32 + n * 16 + lrow;
#pragma unroll
    for (int kk = 0; kk < 2; ++kk)
      boff[n][kk] = r * 128 + ((kk * 64 + lkb) ^ ((r & 7) << 4));
  }

  const size_t ldab = (size_t)K * 2;
  const char* Ab = (const char*)A + (size_t)by * 256 * ldab;
  const char* Bb = (const char*)B + (size_t)bx * 256 * ldab;

  // staging: half = 128 rows x 128B; 2 issues/thread; linear LDS dest,
  // inverse-swizzled global source (both-sides involution, rule #21)
  size_t g2[2];
#pragma unroll
  for (int i = 0; i < 2; ++i) {
    int X = i * 8192 + tid * 16;
    int srow = X >> 7;
    g2[i] = (size_t)srow * ldab + (size_t)((X & 127) ^ ((srow & 7) << 4));
  }

  // half index: 0=A0, 1=A1, 2=B0, 3=B1 at offset half*16384
  auto stage = [&](int Tt, int half) {
    char* dst = smem + ((Tt & 1) * 65536 + half * 16384) + tid * 16;
    const char* src = (half < 2 ? Ab + (size_t)(half * 128) * ldab
                                : Bb + (size_t)((half - 2) * 128) * ldab) + (size_t)Tt * 128;
    async16(src + g2[0], dst);
    async16(src + g2[1], dst + 8192);
  };

  const int nkt = K >> 6;
  // prologue: tile0 all 4 halves, tile1 A0+B0; vmcnt(4) -> tile0 landed
  stage(0, 0); stage(0, 2); stage(0, 3); stage(0, 1);
  stage(1, 0); stage(1, 2);
  asm volatile("s_waitcnt vmcnt(4)" ::: "memory");
  __builtin_amdgcn_s_barrier();

  f32x4 acc[8][4];
#pragma unroll
  for (int m = 0; m < 8; ++m)
#pragma unroll
    for (int n = 0; n < 4; ++n) acc[m][n] = (f32x4){0.f, 0.f, 0.f, 0.f};

#define PHASE_PRE(LG8)                                          \
  __builtin_amdgcn_sched_barrier(0);                            \
  if (LG8) asm volatile("s_waitcnt lgkmcnt(8)" ::: "memory");   \
  __builtin_amdgcn_s_barrier();                                 \
  asm volatile("s_waitcnt lgkmcnt(0)" ::: "memory");            \
  __builtin_amdgcn_sched_barrier(0);                            \
  __builtin_amdgcn_s_setprio(1);
#define PHASE_POST                                              \
  __builtin_amdgcn_s_setprio(0);                                \
  __builtin_amdgcn_sched_barrier(0);                            \
  __builtin_amdgcn_s_barrier();

  for (int t = 0; t < nkt; ++t) {
    const char* SA = smem + (t & 1) * 65536;         // A0 @ +0, A1 @ +16384
    const char* SB = SA + 32768;                     // B0 @ +0, B1 @ +16384
    bf16x8 af[4][2], bfr[2][2];

    // ---- P1: Q00 (reads A0,B0; stages B1(t+1)) ----
    if (t + 1 < nkt) stage(t + 1, 3);
#pragma unroll
    for (int m = 0; m < 4; ++m)
#pragma unroll
      for (int kk = 0; kk < 2; ++kk)
        af[m][kk] = *reinterpret_cast<const bf16x8*>(SA + aoff[m][kk]);
#pragma unroll
    for (int n = 0; n < 2; ++n)
#pragma unroll
      for (int kk = 0; kk < 2; ++kk)
        bfr[n][kk] = *reinterpret_cast<const bf16x8*>(SB + boff[n][kk]);
    PHASE_PRE(1)
    quad<0, 0>(acc, af, bfr);
    PHASE_POST

    // ---- P2: Q01 (A0 kept in regs; reads B1; stages A1(t+1)) ----
    if (t + 1 < nkt) stage(t + 1, 1);
#pragma unroll
    for (int n = 0; n < 2; ++n)
#pragma unroll
      for (int kk = 0; kk < 2; ++kk)
        bfr[n][kk] = *reinterpret_cast<const bf16x8*>(SB + 16384 + boff[n][kk]);
    PHASE_PRE(0)
    quad<0, 1>(acc, af, bfr);
    PHASE_POST

    // ---- P3: Q10 (reads A1,B0; stages A0(t+2) -- A0 freed at end of P2) ----
    if (t + 2 < nkt) stage(t + 2, 0);
#pragma unroll
    for (int m = 0; m < 4; ++m)
#pragma unroll
      for (int kk = 0; kk < 2; ++kk)
        af[m][kk] = *reinterpret_cast<const bf16x8*>(SA + 16384 + aoff[m][kk]);
#pragma unroll
    for (int n = 0; n < 2; ++n)
#pragma unroll
      for (int kk = 0; kk < 2; ++kk)
        bfr[n][kk] = *reinterpret_cast<const bf16x8*>(SB + boff[n][kk]);
    PHASE_PRE(1)
    quad<1, 0>(acc, af, bfr);
    PHASE_POST

    // ---- P4: Q11 (A1 kept; reads B1; stages B0(t+2); counted vmcnt) ----
    if (t + 2 < nkt) stage(t + 2, 2);
#pragma unroll
    for (int n = 0; n < 2; ++n)
#pragma unroll
      for (int kk = 0; kk < 2; ++kk)
        bfr[n][kk] = *reinterpret_cast<const bf16x8*>(SB + 16384 + boff[n][kk]);
    __builtin_amdgcn_sched_barrier(0);
    if (t + 2 < nkt) asm volatile("s_waitcnt vmcnt(4)" ::: "memory");
    else             asm volatile("s_waitcnt vmcnt(0)" ::: "memory");
    __builtin_amdgcn_s_barrier();
    asm volatile("s_waitcnt lgkmcnt(0)" ::: "memory");
    __builtin_amdgcn_sched_barrier(0);
    __builtin_amdgcn_s_setprio(1);
    quad<1, 1>(acc, af, bfr);
    PHASE_POST
  }
#undef PHASE_PRE
#undef PHASE_POST

  if (MODE == 0) {
    // virtual 16-col group g16v = bx*16 + hn*8 + wc*2 + n; n=0 gate, n=1 up;
    // real col group rg = bx*8 + hn*4 + wc, col = rg*16 + lrow
    u16* Z = (u16*)outp;
#pragma unroll
    for (int hm = 0; hm < 2; ++hm)
#pragma unroll
      for (int m = 0; m < 4; ++m)
#pragma unroll
        for (int j = 0; j < 4; ++j) {
          int gr = by * 256 + hm * 128 + wr * 64 + m * 16 + ((lane >> 4) << 2) + j;
#pragma unroll
          for (int hn = 0; hn < 2; ++hn) {
            int rg = bx * 8 + hn * 4 + wc;
            u32 w = mask[(size_t)gr * 256 + (rg >> 1)];
            float g = acc[hm * 4 + m][hn * 2 + 0][j];
            float u = acc[hm * 4 + m][hn * 2 + 1][j];
            float z = 0.f;
            if ((w >> ((rg & 1) * 16 + lrow)) & 1u) z = g * u / (1.f + __expf(-g));
            Z[(size_t)gr * DFFN + rg * 16 + lrow] = f2bf(z);
          }
        }
  } else {
    float* O = (float*)outp;
#pragma unroll
    for (int hm = 0; hm < 2; ++hm)
#pragma unroll
      for (int m = 0; m < 4; ++m)
#pragma unroll
        for (int j = 0; j < 4; ++j) {
          int gr = by * 256 + hm * 128 + wr * 64 + m * 16 + ((lane >> 4) << 2) + j;
#pragma unroll
          for (int hn = 0; hn < 2; ++hn)
#pragma unroll
            for (int n = 0; n < 2; ++n) {
              int gc = bx * 256 + hn * 128 + wc * 32 + n * 16 + lrow;
              O[(size_t)gr * DMODEL + gc] = acc[hm * 4 + m][hn * 2 + n][j];
            }
        }
  }
}

extern "C" void kernel_launch(void* const* d_in, const int* in_sizes, int n_in,
                              void* d_out, int out_size, void* d_ws, size_t ws_size,
                              hipStream_t stream) {
  (void)in_sizes; (void)n_in; (void)out_size; (void)ws_size;
  const float* x   = (const float*)d_in[0];
  const u32*   ix  = (const u32*)d_in[1];
  const float* wg  = (const float*)d_in[2];
  const float* wu  = (const float*)d_in[3];
  const float* wd  = (const float*)d_in[4];

  // ws layout (232 MB): [0,32) xb (then wdT aliases); [32,96) wcomb; [96,224) Zb; [224,232) mask
  char* ws = (char*)d_ws;
  u16* xb    = (u16*)(ws);
  u16* wcomb = (u16*)(ws + (size_t)32 * 1048576);
  u16* Zb    = (u16*)(ws + (size_t)96 * 1048576);
  u32* mask  = (u32*)(ws + (size_t)224 * 1048576);
  u16* wdT   = (u16*)(ws);  // aliases xb, used only after GEMM1

  conv_bf16x4<<<(M_ROWS * DMODEL / 4 + 255) / 256, 256, 0, stream>>>(x, xb, M_ROWS * DMODEL / 4);
  dim3 tgrid(DFFN / 64, DMODEL / 64);
  transpose_conv<1><<<tgrid, 256, 0, stream>>>(wg, wcomb, DMODEL, DFFN, 0);
  transpose_conv<1><<<tgrid, 256, 0, stream>>>(wu, wcomb, DMODEL, DFFN, 1);
  hipMemsetAsync(mask, 0, (size_t)M_ROWS * 256 * 4, stream);
  build_mask<<<(M_ROWS * 512 + 255) / 256, 256, 0, stream>>>(ix, mask, M_ROWS * 512);
  // GEMM1: virtual N = 16384 interleaved gate/up, BN=256 -> NBX=64
  gemm_bt<0, 2 * DFFN / 256, M_ROWS / 256>
      <<<(2 * DFFN / 256) * (M_ROWS / 256), 512, 0, stream>>>(xb, wcomb, DMODEL, Zb, mask);
  dim3 dgrid(DMODEL / 64, DFFN / 64);
  transpose_conv<0><<<dgrid, 256, 0, stream>>>(wd, wdT, DFFN, DMODEL, 0);
  // GEMM2: Y = Z @ Wd, BN=256 -> NBX=8
  gemm_bt<1, DMODEL / 256, M_ROWS / 256>
      <<<(DMODEL / 256) * (M_ROWS / 256), 512, 0, stream>>>(Zb, wdT, DFFN, d_out, nullptr);
}